// Round 1
// baseline (5499.446 us; speedup 1.0000x reference)
//
#include <hip/hip_runtime.h>
#include <hip/hip_bf16.h>

#define N_NODES 50000
#define N_EDGES 800000
#define DIM 128
#define NLAYERS 4
#define BN_EPS 1e-5f
#define ECH 64   // edges per block in edge passes

typedef unsigned short bf16_t;
typedef __attribute__((ext_vector_type(8))) short bf16x8;
typedef __attribute__((ext_vector_type(4))) float f32x4;

__device__ __forceinline__ float bf2f(bf16_t x) {
    unsigned int u = ((unsigned int)x) << 16;
    return __uint_as_float(u);
}
__device__ __forceinline__ bf16_t f2bf(float f) {
    unsigned int u = __float_as_uint(f);
    unsigned int r = (u + 0x7FFFu + ((u >> 16) & 1u)) >> 16;  // round-nearest-even
    return (bf16_t)r;
}

// ---- 5 node projections: A,B,U,Vf,Vb = h @ W^T + b  (bf16 out) ----
__global__ __launch_bounds__(128) void node_gemm(
    const float* __restrict__ h,
    const float* __restrict__ WA, const float* __restrict__ bA,
    const float* __restrict__ WB, const float* __restrict__ bB,
    const float* __restrict__ WU, const float* __restrict__ bU,
    const float* __restrict__ WVf, const float* __restrict__ bVf,
    const float* __restrict__ WVb, const float* __restrict__ bVb,
    bf16_t* __restrict__ A, bf16_t* __restrict__ B, bf16_t* __restrict__ U,
    bf16_t* __restrict__ Vf, bf16_t* __restrict__ Vb)
{
    __shared__ float hl[8][DIM];
    const int t = threadIdx.x;
    const long n0 = (long)blockIdx.x * 8;
    #pragma unroll
    for (int i = 0; i < 8; ++i) hl[i][t] = h[(n0 + i) * DIM + t];
    __syncthreads();

    const float* Ws[5] = {WA, WB, WU, WVf, WVb};
    const float* bs[5] = {bA, bB, bU, bVf, bVb};
    float acc[5][8];
    #pragma unroll
    for (int m = 0; m < 5; ++m) {
        float bv = bs[m][t];
        #pragma unroll
        for (int n = 0; n < 8; ++n) acc[m][n] = bv;
    }
    const float4* wr[5];
    #pragma unroll
    for (int m = 0; m < 5; ++m) wr[m] = (const float4*)(Ws[m] + (size_t)t * DIM);

    #pragma unroll 4
    for (int j4 = 0; j4 < DIM / 4; ++j4) {
        float4 h4[8];
        #pragma unroll
        for (int n = 0; n < 8; ++n) h4[n] = ((const float4*)hl[n])[j4];
        #pragma unroll
        for (int m = 0; m < 5; ++m) {
            float4 w = wr[m][j4];
            #pragma unroll
            for (int n = 0; n < 8; ++n)
                acc[m][n] += w.x * h4[n].x + w.y * h4[n].y + w.z * h4[n].z + w.w * h4[n].w;
        }
    }
    bf16_t* Os[5] = {A, B, U, Vf, Vb};
    #pragma unroll
    for (int m = 0; m < 5; ++m)
        #pragma unroll
        for (int n = 0; n < 8; ++n)
            Os[m][(n0 + n) * DIM + t] = f2bf(acc[m][n]);
}

// ---- C = e @ WC^T + bC  (bf16 out), MFMA 16x16x32 bf16 ----
// Tile: 64 edges x 128 features per block iteration, 4 waves (wave w owns
// features [32w, 32w+32)). Weights live in registers for the whole kernel
// (8 bf16x8 frags/lane). e is staged fp32->bf16 into XOR-swizzled LDS,
// double-buffered, one barrier per tile. Next-tile global loads are issued
// before the MFMA cluster so HBM latency hides under compute.
#define EG_TILE 64
#define EG_TILES 5
#define EG_GRID (N_EDGES / (EG_TILE * EG_TILES))   // 2500

__global__ __launch_bounds__(256) void edge_gemm_mfma(
    const float* __restrict__ e, const float* __restrict__ WC,
    const float* __restrict__ bC, bf16_t* __restrict__ C)
{
    __shared__ __align__(16) char elds[2][EG_TILE * 256];  // 2 x 16KB bf16 tiles

    const int tid  = threadIdx.x;
    const int lane = tid & 63;
    const int wv   = tid >> 6;     // wave 0..3 -> feature block
    const int l16  = lane & 15;
    const int lk   = lane >> 4;    // 0..3

    // ---- weight fragments, held in registers for all tiles ----
    // B[k][n] = WC[n][k]; lane holds col n = wv*32 + nt*16 + l16,
    // k = ks*32 + lk*8 .. +8 (8 consecutive fp32 of one WC row).
    bf16x8 bfrag[2][4];
    float bias[2];
    #pragma unroll
    for (int nt = 0; nt < 2; ++nt) {
        const int n = wv * 32 + nt * 16 + l16;
        bias[nt] = bC[n];
        #pragma unroll
        for (int ks = 0; ks < 4; ++ks) {
            const int k = ks * 32 + lk * 8;
            const float4* wp = (const float4*)(WC + (size_t)n * DIM + k);
            float4 w0 = wp[0], w1 = wp[1];
            union { bf16x8 v; bf16_t s[8]; } u;
            u.s[0] = f2bf(w0.x); u.s[1] = f2bf(w0.y);
            u.s[2] = f2bf(w0.z); u.s[3] = f2bf(w0.w);
            u.s[4] = f2bf(w1.x); u.s[5] = f2bf(w1.y);
            u.s[6] = f2bf(w1.z); u.s[7] = f2bf(w1.w);
            bfrag[nt][ks] = u.v;
        }
    }

    // staging: 1024 16B-chunks per tile (64 rows x 16), 4 chunks/thread
    float4 sreg[4][2];
    const long tile0 = (long)blockIdx.x * EG_TILES;

    auto load_tile = [&](long tile) {
        #pragma unroll
        for (int j = 0; j < 4; ++j) {
            const int idx = j * 256 + tid;
            const int row = idx >> 4, cb = idx & 15;
            const float4* gp = (const float4*)(
                e + (size_t)(tile * EG_TILE + row) * DIM + cb * 8);
            sreg[j][0] = gp[0]; sreg[j][1] = gp[1];
        }
    };
    auto write_lds = [&](int buf) {
        #pragma unroll
        for (int j = 0; j < 4; ++j) {
            const int idx = j * 256 + tid;
            const int row = idx >> 4, cb = idx & 15;
            union { bf16x8 v; bf16_t s[8]; } u;
            float4 a = sreg[j][0], b = sreg[j][1];
            u.s[0] = f2bf(a.x); u.s[1] = f2bf(a.y);
            u.s[2] = f2bf(a.z); u.s[3] = f2bf(a.w);
            u.s[4] = f2bf(b.x); u.s[5] = f2bf(b.y);
            u.s[6] = f2bf(b.z); u.s[7] = f2bf(b.w);
            const int off = row * 256 + ((cb * 16) ^ ((row & 7) << 4));
            *(bf16x8*)(&elds[buf][off]) = u.v;
        }
    };

    load_tile(tile0);
    write_lds(0);
    __syncthreads();
    int cur = 0;

    for (int t = 0; t < EG_TILES; ++t) {
        if (t + 1 < EG_TILES) load_tile(tile0 + t + 1);  // issue early

        f32x4 acc[4][2];
        #pragma unroll
        for (int mt = 0; mt < 4; ++mt)
            #pragma unroll
            for (int nt = 0; nt < 2; ++nt)
                acc[mt][nt] = (f32x4){0.f, 0.f, 0.f, 0.f};

        #pragma unroll
        for (int ks = 0; ks < 4; ++ks) {
            bf16x8 afrag[4];
            #pragma unroll
            for (int mt = 0; mt < 4; ++mt) {
                const int row = mt * 16 + l16;
                const int off = row * 256 +
                    ((ks * 64 + lk * 16) ^ ((row & 7) << 4));
                afrag[mt] = *(const bf16x8*)(&elds[cur][off]);
            }
            #pragma unroll
            for (int mt = 0; mt < 4; ++mt)
                #pragma unroll
                for (int nt = 0; nt < 2; ++nt)
                    acc[mt][nt] = __builtin_amdgcn_mfma_f32_16x16x32_bf16(
                        afrag[mt], bfrag[nt][ks], acc[mt][nt], 0, 0, 0);
        }

        // C/D layout: row = lk*4 + r, col = l16 (m89-verified)
        const long e0 = (tile0 + t) * EG_TILE;
        #pragma unroll
        for (int mt = 0; mt < 4; ++mt) {
            const long rbase = e0 + mt * 16 + lk * 4;
            #pragma unroll
            for (int nt = 0; nt < 2; ++nt) {
                const int col = wv * 32 + nt * 16 + l16;
                #pragma unroll
                for (int r = 0; r < 4; ++r)
                    C[(rbase + r) * DIM + col] = f2bf(acc[mt][nt][r] + bias[nt]);
            }
        }

        if (t + 1 < EG_TILES) {
            write_lds(cur ^ 1);
            __syncthreads();
            cur ^= 1;
        }
    }
}

// ---- edge BN stats for both gates (sum & sumsq per feature) ----
__global__ __launch_bounds__(128) void edge_stats(
    const int* __restrict__ s0, const int* __restrict__ s1,
    const bf16_t* __restrict__ A, const bf16_t* __restrict__ B,
    const bf16_t* __restrict__ C, float* __restrict__ stats)
{
    __shared__ int ls0[ECH], ls1[ECH];
    const int t = threadIdx.x;
    const long k0 = (long)blockIdx.x * ECH;
    if (t < ECH) { ls0[t] = s0[k0 + t]; ls1[t] = s1[k0 + t]; }
    __syncthreads();

    float sf = 0.f, ssf = 0.f, sb = 0.f, ssb = 0.f;
    for (int i = 0; i < ECH; ++i) {
        const long k = k0 + i;
        const long a = ls0[i], b = ls1[i];
        float c  = bf2f(C[k * DIM + t]);
        float a0 = bf2f(A[a * DIM + t]);
        float b1 = bf2f(B[b * DIM + t]);
        float a1 = bf2f(A[b * DIM + t]);
        float b0 = bf2f(B[a * DIM + t]);
        float tf = a0 + b1 + c;
        float tb = a1 + b0 + c;
        sf += tf; ssf += tf * tf;
        sb += tb; ssb += tb * tb;
    }
    atomicAdd(&stats[t], sf);
    atomicAdd(&stats[128 + t], ssf);
    atomicAdd(&stats[256 + t], sb);
    atomicAdd(&stats[384 + t], ssb);
}

__global__ void finalize_edge_stats(float* __restrict__ stats)
{
    const int t = threadIdx.x;
    const float inv = 1.0f / (float)N_EDGES;
    if (t < 128) {
        float mu = stats[t] * inv;
        float var = stats[128 + t] * inv - mu * mu;
        stats[768 + t] = mu;
        stats[896 + t] = rsqrtf(var + BN_EPS);
    } else {
        int d = t - 128;
        float mu = stats[256 + d] * inv;
        float var = stats[384 + d] * inv - mu * mu;
        stats[1024 + d] = mu;
        stats[1152 + d] = rsqrtf(var + BN_EPS);
    }
}

// ---- fused edge apply: e_new (fwd gate), both gate weights, single scatter ----
__global__ __launch_bounds__(128) void edge_apply(
    const int* __restrict__ s0, const int* __restrict__ s1,
    const bf16_t* __restrict__ A, const bf16_t* __restrict__ B,
    const bf16_t* __restrict__ C,
    const bf16_t* __restrict__ Vf, const bf16_t* __restrict__ Vb,
    const float* __restrict__ stats,
    const float* __restrict__ gne, const float* __restrict__ bne,
    float* __restrict__ ebuf, float* __restrict__ agg)
{
    __shared__ int ls0[ECH], ls1[ECH];
    const int t = threadIdx.x;
    const long k0 = (long)blockIdx.x * ECH;
    if (t < ECH) { ls0[t] = s0[k0 + t]; ls1[t] = s1[k0 + t]; }
    __syncthreads();

    const float g = gne[t], bb = bne[t];
    const float af = stats[896 + t] * g;
    const float cf = bb - stats[768 + t] * af;
    const float ab = stats[1152 + t] * g;
    const float cb = bb - stats[1024 + t] * ab;

    for (int i = 0; i < ECH; ++i) {
        const long k = k0 + i;
        const long sa = ls0[i], sd = ls1[i];
        float c  = bf2f(C[k * DIM + t]);
        float a0 = bf2f(A[sa * DIM + t]);
        float b1 = bf2f(B[sd * DIM + t]);
        float a1 = bf2f(A[sd * DIM + t]);
        float b0 = bf2f(B[sa * DIM + t]);
        float ek = ebuf[k * DIM + t];

        float nf = fmaxf((a0 + b1 + c) * af + cf, 0.0f) + ek;  // new e (fwd gate)
        float nb = fmaxf((a1 + b0 + c) * ab + cb, 0.0f) + ek;
        ebuf[k * DIM + t] = nf;

        float sigf = 1.0f / (1.0f + __expf(-nf));
        float sigb = 1.0f / (1.0f + __expf(-nb));
        float wf = sigf / (sigf + 1e-6f);
        float wb = sigb / (sigb + 1e-6f);
        float msg = bf2f(Vf[sa * DIM + t]) * wf + bf2f(Vb[sa * DIM + t]) * wb;
        atomicAdd(&agg[sd * DIM + t], msg);
    }
}

// ---- node BN stats over (agg + U) ----
__global__ __launch_bounds__(128) void node_stats(
    const float* __restrict__ agg, const bf16_t* __restrict__ U,
    float* __restrict__ stats)
{
    const int t = threadIdx.x;
    const long n0 = (long)blockIdx.x * 50;
    float s = 0.f, ss = 0.f;
    for (int i = 0; i < 50; ++i) {
        const long n = n0 + i;
        float v = agg[n * DIM + t] + bf2f(U[n * DIM + t]);
        s += v; ss += v * v;
    }
    atomicAdd(&stats[512 + t], s);
    atomicAdd(&stats[640 + t], ss);
}

__global__ void finalize_node_stats(float* __restrict__ stats)
{
    const int t = threadIdx.x;
    const float inv = 1.0f / (float)N_NODES;
    float mu = stats[512 + t] * inv;
    float var = stats[640 + t] * inv - mu * mu;
    stats[1280 + t] = mu;
    stats[1408 + t] = rsqrtf(var + BN_EPS);
}

// ---- h_new = relu(bn(agg+U)) + h, in place ----
__global__ __launch_bounds__(256) void node_apply(
    const float* __restrict__ agg, const bf16_t* __restrict__ U,
    const float* __restrict__ stats,
    const float* __restrict__ gh, const float* __restrict__ bh,
    float* __restrict__ hbuf)
{
    const long i = (long)blockIdx.x * 256 + threadIdx.x;
    const int d = (int)(i & (DIM - 1));
    float v = agg[i] + bf2f(U[i]);
    float n = (v - stats[1280 + d]) * stats[1408 + d] * gh[d] + bh[d];
    hbuf[i] = fmaxf(n, 0.0f) + hbuf[i];
}

extern "C" void kernel_launch(void* const* d_in, const int* in_sizes, int n_in,
                              void* d_out, int out_size, void* d_ws, size_t ws_size,
                              hipStream_t stream)
{
    const int* ei = (const int*)d_in[0];
    const int* s0 = ei;
    const int* s1 = ei + N_EDGES;
    const float* h0 = (const float*)d_in[1];
    const float* e0 = (const float*)d_in[2];
    const float* WA = (const float*)d_in[3];  const float* bA = (const float*)d_in[4];
    const float* WB = (const float*)d_in[5];  const float* bB = (const float*)d_in[6];
    const float* WC = (const float*)d_in[7];  const float* bC = (const float*)d_in[8];
    const float* WU = (const float*)d_in[9];  const float* bU = (const float*)d_in[10];
    const float* WVf = (const float*)d_in[11]; const float* bVf = (const float*)d_in[12];
    const float* WVb = (const float*)d_in[13]; const float* bVb = (const float*)d_in[14];
    const float* bnh_g = (const float*)d_in[15]; const float* bnh_b = (const float*)d_in[16];
    const float* bne_g = (const float*)d_in[17]; const float* bne_b = (const float*)d_in[18];

    float* hbuf = (float*)d_out;                       // N*D f32 (live h)
    float* ebuf = hbuf + (size_t)N_NODES * DIM;        // E*D f32 (live e)

    float* agg = (float*)d_ws;                         // N*D f32
    float* stats = agg + (size_t)N_NODES * DIM;        // 2048 f32
    bf16_t* Abuf  = (bf16_t*)(stats + 2048);
    bf16_t* Bbuf  = Abuf  + (size_t)N_NODES * DIM;
    bf16_t* Ubuf  = Bbuf  + (size_t)N_NODES * DIM;
    bf16_t* Vfbuf = Ubuf  + (size_t)N_NODES * DIM;
    bf16_t* Vbbuf = Vfbuf + (size_t)N_NODES * DIM;
    bf16_t* Cbuf  = Vbbuf + (size_t)N_NODES * DIM;     // E*D bf16

    hipMemcpyAsync(hbuf, h0, (size_t)N_NODES * DIM * sizeof(float),
                   hipMemcpyDeviceToDevice, stream);
    hipMemcpyAsync(ebuf, e0, (size_t)N_EDGES * DIM * sizeof(float),
                   hipMemcpyDeviceToDevice, stream);

    for (int l = 0; l < NLAYERS; ++l) {
        const size_t wo = (size_t)l * DIM * DIM;
        const size_t bo = (size_t)l * DIM;
        // zero agg + the 6 sum arrays (first 768 floats of stats)
        hipMemsetAsync(agg, 0, ((size_t)N_NODES * DIM + 768) * sizeof(float), stream);

        node_gemm<<<N_NODES / 8, 128, 0, stream>>>(
            hbuf, WA + wo, bA + bo, WB + wo, bB + bo, WU + wo, bU + bo,
            WVf + wo, bVf + bo, WVb + wo, bVb + bo,
            Abuf, Bbuf, Ubuf, Vfbuf, Vbbuf);
        edge_gemm_mfma<<<EG_GRID, 256, 0, stream>>>(ebuf, WC + wo, bC + bo, Cbuf);
        edge_stats<<<N_EDGES / ECH, 128, 0, stream>>>(s0, s1, Abuf, Bbuf, Cbuf, stats);
        finalize_edge_stats<<<1, 256, 0, stream>>>(stats);
        edge_apply<<<N_EDGES / ECH, 128, 0, stream>>>(
            s0, s1, Abuf, Bbuf, Cbuf, Vfbuf, Vbbuf, stats,
            bne_g + bo, bne_b + bo, ebuf, agg);
        node_stats<<<N_NODES / 50, 128, 0, stream>>>(agg, Ubuf, stats);
        finalize_node_stats<<<1, 128, 0, stream>>>(stats);
        node_apply<<<(N_NODES * DIM) / 256, 256, 0, stream>>>(
            agg, Ubuf, stats, bnh_g + bo, bnh_b + bo, hbuf);
    }
}

// Round 2
// 4601.496 us; speedup vs baseline: 1.1951x; 1.1951x over previous
//
#include <hip/hip_runtime.h>
#include <hip/hip_bf16.h>

#define N_NODES 50000
#define N_EDGES 800000
#define DIM 128
#define NLAYERS 4
#define BN_EPS 1e-5f
#define ECH 64   // edges per block in edge passes

typedef unsigned short bf16_t;
typedef __attribute__((ext_vector_type(8))) short bf16x8;
typedef __attribute__((ext_vector_type(4))) float f32x4;

__device__ __forceinline__ float bf2f(bf16_t x) {
    unsigned int u = ((unsigned int)x) << 16;
    return __uint_as_float(u);
}
__device__ __forceinline__ bf16_t f2bf(float f) {
    unsigned int u = __float_as_uint(f);
    unsigned int r = (u + 0x7FFFu + ((u >> 16) & 1u)) >> 16;  // round-nearest-even
    return (bf16_t)r;
}

// ================= one-time edge sort by destination =================
__global__ __launch_bounds__(256) void hist_kernel(
    const int* __restrict__ s1, int* __restrict__ deg)
{
    int k = blockIdx.x * 256 + threadIdx.x;
    if (k < N_EDGES) atomicAdd(&deg[s1[k]], 1);
}

__global__ __launch_bounds__(1024) void scan_kernel(
    const int* __restrict__ deg, int* __restrict__ cursor)
{
    __shared__ int part[1024];
    const int t = threadIdx.x;
    const int CH = (N_NODES + 1023) / 1024;  // 49
    const int base = t * CH;
    int s = 0;
    for (int i = 0; i < CH; ++i) {
        int n = base + i;
        if (n < N_NODES) s += deg[n];
    }
    part[t] = s;
    __syncthreads();
    for (int off = 1; off < 1024; off <<= 1) {
        int v = (t >= off) ? part[t - off] : 0;
        __syncthreads();
        part[t] += v;
        __syncthreads();
    }
    int run = part[t] - s;  // exclusive prefix
    for (int i = 0; i < CH; ++i) {
        int n = base + i;
        if (n < N_NODES) { cursor[n] = run; run += deg[n]; }
    }
}

__global__ __launch_bounds__(256) void scatter_kernel(
    const int* __restrict__ s0, const int* __restrict__ s1,
    int* __restrict__ cursor, int* __restrict__ perm,
    int* __restrict__ ssrc, int* __restrict__ sdst)
{
    int k = blockIdx.x * 256 + threadIdx.x;
    if (k < N_EDGES) {
        int d = s1[k];
        int pos = atomicAdd(&cursor[d], 1);
        perm[pos] = k;
        ssrc[pos] = s0[k];
        sdst[pos] = d;
    }
}

// ---- 5 node projections via MFMA: A,B,U,Vf,Vb = h @ W^T + b (bf16 out) ----
#define NG_TILE 64
#define NG_GRID ((N_NODES + NG_TILE - 1) / NG_TILE)  // 782

__global__ __launch_bounds__(256) void node_gemm_mfma(
    const float* __restrict__ h,
    const float* __restrict__ WA, const float* __restrict__ bA,
    const float* __restrict__ WB, const float* __restrict__ bB,
    const float* __restrict__ WU, const float* __restrict__ bU,
    const float* __restrict__ WVf, const float* __restrict__ bVf,
    const float* __restrict__ WVb, const float* __restrict__ bVb,
    bf16_t* __restrict__ A, bf16_t* __restrict__ B, bf16_t* __restrict__ U,
    bf16_t* __restrict__ Vf, bf16_t* __restrict__ Vb)
{
    __shared__ __align__(16) char hlds[NG_TILE * 256];

    const int tid  = threadIdx.x;
    const int lane = tid & 63;
    const int wv   = tid >> 6;
    const int l16  = lane & 15;
    const int lk   = lane >> 4;
    const long n0  = (long)blockIdx.x * NG_TILE;

    // stage h tile f32 -> bf16, XOR-swizzled
    #pragma unroll
    for (int j = 0; j < 4; ++j) {
        const int idx = j * 256 + tid;
        const int row = idx >> 4, cb = idx & 15;
        long r = n0 + row;
        if (r >= N_NODES) r = N_NODES - 1;   // clamp (stores are guarded)
        const float4* gp = (const float4*)(h + (size_t)r * DIM + cb * 8);
        float4 a = gp[0], b = gp[1];
        union { bf16x8 v; bf16_t s[8]; } u;
        u.s[0] = f2bf(a.x); u.s[1] = f2bf(a.y);
        u.s[2] = f2bf(a.z); u.s[3] = f2bf(a.w);
        u.s[4] = f2bf(b.x); u.s[5] = f2bf(b.y);
        u.s[6] = f2bf(b.z); u.s[7] = f2bf(b.w);
        const int off = row * 256 + ((cb * 16) ^ ((row & 7) << 4));
        *(bf16x8*)(&hlds[off]) = u.v;
    }
    __syncthreads();

    // A-frags from LDS once, reused across the 5 matrices
    bf16x8 afrag[4][4];  // [ks][mt]
    #pragma unroll
    for (int ks = 0; ks < 4; ++ks)
        #pragma unroll
        for (int mt = 0; mt < 4; ++mt) {
            const int row = mt * 16 + l16;
            const int off = row * 256 + ((ks * 64 + lk * 16) ^ ((row & 7) << 4));
            afrag[ks][mt] = *(const bf16x8*)(&hlds[off]);
        }

    const float* Ws[5] = {WA, WB, WU, WVf, WVb};
    const float* bs[5] = {bA, bB, bU, bVf, bVb};
    bf16_t* Os[5] = {A, B, U, Vf, Vb};

    #pragma unroll
    for (int m = 0; m < 5; ++m) {
        bf16x8 bfrag[2][4];
        float bias[2];
        #pragma unroll
        for (int nt = 0; nt < 2; ++nt) {
            const int n = wv * 32 + nt * 16 + l16;
            bias[nt] = bs[m][n];
            #pragma unroll
            for (int ks = 0; ks < 4; ++ks) {
                const int k = ks * 32 + lk * 8;
                const float4* wp = (const float4*)(Ws[m] + (size_t)n * DIM + k);
                float4 w0 = wp[0], w1 = wp[1];
                union { bf16x8 v; bf16_t s[8]; } u;
                u.s[0] = f2bf(w0.x); u.s[1] = f2bf(w0.y);
                u.s[2] = f2bf(w0.z); u.s[3] = f2bf(w0.w);
                u.s[4] = f2bf(w1.x); u.s[5] = f2bf(w1.y);
                u.s[6] = f2bf(w1.z); u.s[7] = f2bf(w1.w);
                bfrag[nt][ks] = u.v;
            }
        }

        f32x4 acc[4][2];
        #pragma unroll
        for (int mt = 0; mt < 4; ++mt)
            #pragma unroll
            for (int nt = 0; nt < 2; ++nt)
                acc[mt][nt] = (f32x4){0.f, 0.f, 0.f, 0.f};

        #pragma unroll
        for (int ks = 0; ks < 4; ++ks)
            #pragma unroll
            for (int mt = 0; mt < 4; ++mt)
                #pragma unroll
                for (int nt = 0; nt < 2; ++nt)
                    acc[mt][nt] = __builtin_amdgcn_mfma_f32_16x16x32_bf16(
                        afrag[ks][mt], bfrag[nt][ks], acc[mt][nt], 0, 0, 0);

        // C/D layout: row = lk*4 + r, col = l16
        #pragma unroll
        for (int mt = 0; mt < 4; ++mt) {
            const long rbase = n0 + mt * 16 + lk * 4;
            #pragma unroll
            for (int nt = 0; nt < 2; ++nt) {
                const int col = wv * 32 + nt * 16 + l16;
                #pragma unroll
                for (int r = 0; r < 4; ++r) {
                    const long rr = rbase + r;
                    if (rr < N_NODES)
                        Os[m][rr * DIM + col] = f2bf(acc[mt][nt][r] + bias[nt]);
                }
            }
        }
    }
}

// ---- C = e @ WC^T + bC  (bf16 out), MFMA 16x16x32 bf16 ----
#define EG_TILE 64
#define EG_TILES 5
#define EG_GRID (N_EDGES / (EG_TILE * EG_TILES))   // 2500

__global__ __launch_bounds__(256) void edge_gemm_mfma(
    const float* __restrict__ e, const float* __restrict__ WC,
    const float* __restrict__ bC, bf16_t* __restrict__ C)
{
    __shared__ __align__(16) char elds[2][EG_TILE * 256];  // 2 x 16KB bf16 tiles

    const int tid  = threadIdx.x;
    const int lane = tid & 63;
    const int wv   = tid >> 6;     // wave 0..3 -> feature block
    const int l16  = lane & 15;
    const int lk   = lane >> 4;    // 0..3

    bf16x8 bfrag[2][4];
    float bias[2];
    #pragma unroll
    for (int nt = 0; nt < 2; ++nt) {
        const int n = wv * 32 + nt * 16 + l16;
        bias[nt] = bC[n];
        #pragma unroll
        for (int ks = 0; ks < 4; ++ks) {
            const int k = ks * 32 + lk * 8;
            const float4* wp = (const float4*)(WC + (size_t)n * DIM + k);
            float4 w0 = wp[0], w1 = wp[1];
            union { bf16x8 v; bf16_t s[8]; } u;
            u.s[0] = f2bf(w0.x); u.s[1] = f2bf(w0.y);
            u.s[2] = f2bf(w0.z); u.s[3] = f2bf(w0.w);
            u.s[4] = f2bf(w1.x); u.s[5] = f2bf(w1.y);
            u.s[6] = f2bf(w1.z); u.s[7] = f2bf(w1.w);
            bfrag[nt][ks] = u.v;
        }
    }

    float4 sreg[4][2];
    const long tile0 = (long)blockIdx.x * EG_TILES;

    auto load_tile = [&](long tile) {
        #pragma unroll
        for (int j = 0; j < 4; ++j) {
            const int idx = j * 256 + tid;
            const int row = idx >> 4, cb = idx & 15;
            const float4* gp = (const float4*)(
                e + (size_t)(tile * EG_TILE + row) * DIM + cb * 8);
            sreg[j][0] = gp[0]; sreg[j][1] = gp[1];
        }
    };
    auto write_lds = [&](int buf) {
        #pragma unroll
        for (int j = 0; j < 4; ++j) {
            const int idx = j * 256 + tid;
            const int row = idx >> 4, cb = idx & 15;
            union { bf16x8 v; bf16_t s[8]; } u;
            float4 a = sreg[j][0], b = sreg[j][1];
            u.s[0] = f2bf(a.x); u.s[1] = f2bf(a.y);
            u.s[2] = f2bf(a.z); u.s[3] = f2bf(a.w);
            u.s[4] = f2bf(b.x); u.s[5] = f2bf(b.y);
            u.s[6] = f2bf(b.z); u.s[7] = f2bf(b.w);
            const int off = row * 256 + ((cb * 16) ^ ((row & 7) << 4));
            *(bf16x8*)(&elds[buf][off]) = u.v;
        }
    };

    load_tile(tile0);
    write_lds(0);
    __syncthreads();
    int cur = 0;

    for (int t = 0; t < EG_TILES; ++t) {
        if (t + 1 < EG_TILES) load_tile(tile0 + t + 1);  // issue early

        f32x4 acc[4][2];
        #pragma unroll
        for (int mt = 0; mt < 4; ++mt)
            #pragma unroll
            for (int nt = 0; nt < 2; ++nt)
                acc[mt][nt] = (f32x4){0.f, 0.f, 0.f, 0.f};

        #pragma unroll
        for (int ks = 0; ks < 4; ++ks) {
            bf16x8 afrag[4];
            #pragma unroll
            for (int mt = 0; mt < 4; ++mt) {
                const int row = mt * 16 + l16;
                const int off = row * 256 +
                    ((ks * 64 + lk * 16) ^ ((row & 7) << 4));
                afrag[mt] = *(const bf16x8*)(&elds[cur][off]);
            }
            #pragma unroll
            for (int mt = 0; mt < 4; ++mt)
                #pragma unroll
                for (int nt = 0; nt < 2; ++nt)
                    acc[mt][nt] = __builtin_amdgcn_mfma_f32_16x16x32_bf16(
                        afrag[mt], bfrag[nt][ks], acc[mt][nt], 0, 0, 0);
        }

        const long e0 = (tile0 + t) * EG_TILE;
        #pragma unroll
        for (int mt = 0; mt < 4; ++mt) {
            const long rbase = e0 + mt * 16 + lk * 4;
            #pragma unroll
            for (int nt = 0; nt < 2; ++nt) {
                const int col = wv * 32 + nt * 16 + l16;
                #pragma unroll
                for (int r = 0; r < 4; ++r)
                    C[(rbase + r) * DIM + col] = f2bf(acc[mt][nt][r] + bias[nt]);
            }
        }

        if (t + 1 < EG_TILES) {
            write_lds(cur ^ 1);
            __syncthreads();
            cur ^= 1;
        }
    }
}

// ---- edge BN stats for both gates (sum & sumsq per feature) ----
__global__ __launch_bounds__(128) void edge_stats(
    const int* __restrict__ s0, const int* __restrict__ s1,
    const bf16_t* __restrict__ A, const bf16_t* __restrict__ B,
    const bf16_t* __restrict__ C, float* __restrict__ stats)
{
    __shared__ int ls0[ECH], ls1[ECH];
    const int t = threadIdx.x;
    const long k0 = (long)blockIdx.x * ECH;
    if (t < ECH) { ls0[t] = s0[k0 + t]; ls1[t] = s1[k0 + t]; }
    __syncthreads();

    float sf = 0.f, ssf = 0.f, sb = 0.f, ssb = 0.f;
    for (int i = 0; i < ECH; ++i) {
        const long k = k0 + i;
        const long a = ls0[i], b = ls1[i];
        float c  = bf2f(C[k * DIM + t]);
        float a0 = bf2f(A[a * DIM + t]);
        float b1 = bf2f(B[b * DIM + t]);
        float a1 = bf2f(A[b * DIM + t]);
        float b0 = bf2f(B[a * DIM + t]);
        float tf = a0 + b1 + c;
        float tb = a1 + b0 + c;
        sf += tf; ssf += tf * tf;
        sb += tb; ssb += tb * tb;
    }
    atomicAdd(&stats[t], sf);
    atomicAdd(&stats[128 + t], ssf);
    atomicAdd(&stats[256 + t], sb);
    atomicAdd(&stats[384 + t], ssb);
}

__global__ void finalize_edge_stats(float* __restrict__ stats)
{
    const int t = threadIdx.x;
    const float inv = 1.0f / (float)N_EDGES;
    if (t < 128) {
        float mu = stats[t] * inv;
        float var = stats[128 + t] * inv - mu * mu;
        stats[768 + t] = mu;
        stats[896 + t] = rsqrtf(var + BN_EPS);
    } else {
        int d = t - 128;
        float mu = stats[256 + d] * inv;
        float var = stats[384 + d] * inv - mu * mu;
        stats[1024 + d] = mu;
        stats[1152 + d] = rsqrtf(var + BN_EPS);
    }
}

// ---- fused edge apply over dest-sorted edges: registers accumulate per
// segment, one atomicAdd per (block,segment) instead of per edge ----
__global__ __launch_bounds__(128) void edge_apply_sorted(
    const int* __restrict__ perm, const int* __restrict__ ssrc,
    const int* __restrict__ sdst,
    const bf16_t* __restrict__ A, const bf16_t* __restrict__ B,
    const bf16_t* __restrict__ C,
    const bf16_t* __restrict__ Vf, const bf16_t* __restrict__ Vb,
    const float* __restrict__ stats,
    const float* __restrict__ gne, const float* __restrict__ bne,
    float* __restrict__ ebuf, float* __restrict__ agg)
{
    __shared__ int lp[ECH], lsa[ECH], lsd[ECH];
    const int t = threadIdx.x;
    const long p0 = (long)blockIdx.x * ECH;
    if (t < ECH) {
        lp[t]  = perm[p0 + t];
        lsa[t] = ssrc[p0 + t];
        lsd[t] = sdst[p0 + t];
    }
    __syncthreads();

    const float g = gne[t], bb = bne[t];
    const float af = stats[896 + t] * g;
    const float cf = bb - stats[768 + t] * af;
    const float ab = stats[1152 + t] * g;
    const float cb = bb - stats[1024 + t] * ab;

    int cur = lsd[0];
    float Ad = bf2f(A[(long)cur * DIM + t]);   // A[s1] for backward gate
    float Bd = bf2f(B[(long)cur * DIM + t]);   // B[s1] for forward gate
    float acc = 0.f;

    for (int i = 0; i < ECH; ++i) {
        const int sd = lsd[i];
        if (sd != cur) {                        // uniform across threads
            atomicAdd(&agg[(long)cur * DIM + t], acc);
            acc = 0.f;
            cur = sd;
            Ad = bf2f(A[(long)cur * DIM + t]);
            Bd = bf2f(B[(long)cur * DIM + t]);
        }
        const long k  = lp[i];
        const long sa = lsa[i];
        float c  = bf2f(C[k * DIM + t]);
        float a0 = bf2f(A[sa * DIM + t]);
        float b0 = bf2f(B[sa * DIM + t]);
        float ek = ebuf[k * DIM + t];

        float nf = fmaxf((a0 + Bd + c) * af + cf, 0.0f) + ek;  // new e (fwd)
        float nb = fmaxf((Ad + b0 + c) * ab + cb, 0.0f) + ek;
        ebuf[k * DIM + t] = nf;

        float sigf = 1.0f / (1.0f + __expf(-nf));
        float sigb = 1.0f / (1.0f + __expf(-nb));
        float wf = sigf / (sigf + 1e-6f);
        float wb = sigb / (sigb + 1e-6f);
        acc += bf2f(Vf[sa * DIM + t]) * wf + bf2f(Vb[sa * DIM + t]) * wb;
    }
    atomicAdd(&agg[(long)cur * DIM + t], acc);
}

// ---- node BN stats over (agg + U) ----
__global__ __launch_bounds__(128) void node_stats(
    const float* __restrict__ agg, const bf16_t* __restrict__ U,
    float* __restrict__ stats)
{
    const int t = threadIdx.x;
    const long n0 = (long)blockIdx.x * 50;
    float s = 0.f, ss = 0.f;
    for (int i = 0; i < 50; ++i) {
        const long n = n0 + i;
        float v = agg[n * DIM + t] + bf2f(U[n * DIM + t]);
        s += v; ss += v * v;
    }
    atomicAdd(&stats[512 + t], s);
    atomicAdd(&stats[640 + t], ss);
}

__global__ void finalize_node_stats(float* __restrict__ stats)
{
    const int t = threadIdx.x;
    const float inv = 1.0f / (float)N_NODES;
    float mu = stats[512 + t] * inv;
    float var = stats[640 + t] * inv - mu * mu;
    stats[1280 + t] = mu;
    stats[1408 + t] = rsqrtf(var + BN_EPS);
}

// ---- h_new = relu(bn(agg+U)) + h, in place ----
__global__ __launch_bounds__(256) void node_apply(
    const float* __restrict__ agg, const bf16_t* __restrict__ U,
    const float* __restrict__ stats,
    const float* __restrict__ gh, const float* __restrict__ bh,
    float* __restrict__ hbuf)
{
    const long i = (long)blockIdx.x * 256 + threadIdx.x;
    const int d = (int)(i & (DIM - 1));
    float v = agg[i] + bf2f(U[i]);
    float n = (v - stats[1280 + d]) * stats[1408 + d] * gh[d] + bh[d];
    hbuf[i] = fmaxf(n, 0.0f) + hbuf[i];
}

extern "C" void kernel_launch(void* const* d_in, const int* in_sizes, int n_in,
                              void* d_out, int out_size, void* d_ws, size_t ws_size,
                              hipStream_t stream)
{
    const int* ei = (const int*)d_in[0];
    const int* s0 = ei;
    const int* s1 = ei + N_EDGES;
    const float* h0 = (const float*)d_in[1];
    const float* e0 = (const float*)d_in[2];
    const float* WA = (const float*)d_in[3];  const float* bA = (const float*)d_in[4];
    const float* WB = (const float*)d_in[5];  const float* bB = (const float*)d_in[6];
    const float* WC = (const float*)d_in[7];  const float* bC = (const float*)d_in[8];
    const float* WU = (const float*)d_in[9];  const float* bU = (const float*)d_in[10];
    const float* WVf = (const float*)d_in[11]; const float* bVf = (const float*)d_in[12];
    const float* WVb = (const float*)d_in[13]; const float* bVb = (const float*)d_in[14];
    const float* bnh_g = (const float*)d_in[15]; const float* bnh_b = (const float*)d_in[16];
    const float* bne_g = (const float*)d_in[17]; const float* bne_b = (const float*)d_in[18];

    float* hbuf = (float*)d_out;                       // N*D f32 (live h)
    float* ebuf = hbuf + (size_t)N_NODES * DIM;        // E*D f32 (live e)

    float* agg = (float*)d_ws;                         // N*D f32
    float* stats = agg + (size_t)N_NODES * DIM;        // 2048 f32
    bf16_t* Abuf  = (bf16_t*)(stats + 2048);
    bf16_t* Bbuf  = Abuf  + (size_t)N_NODES * DIM;
    bf16_t* Ubuf  = Bbuf  + (size_t)N_NODES * DIM;
    bf16_t* Vfbuf = Ubuf  + (size_t)N_NODES * DIM;
    bf16_t* Vbbuf = Vfbuf + (size_t)N_NODES * DIM;
    bf16_t* Cbuf  = Vbbuf + (size_t)N_NODES * DIM;     // E*D bf16
    int* deg    = (int*)(Cbuf + (size_t)N_EDGES * DIM);
    int* cursor = deg + N_NODES;
    int* perm   = cursor + N_NODES;
    int* ssrc   = perm + N_EDGES;
    int* sdst   = ssrc + N_EDGES;

    hipMemcpyAsync(hbuf, h0, (size_t)N_NODES * DIM * sizeof(float),
                   hipMemcpyDeviceToDevice, stream);
    hipMemcpyAsync(ebuf, e0, (size_t)N_EDGES * DIM * sizeof(float),
                   hipMemcpyDeviceToDevice, stream);

    // ---- one-time: counting-sort edges by destination ----
    hipMemsetAsync(deg, 0, N_NODES * sizeof(int), stream);
    hist_kernel<<<(N_EDGES + 255) / 256, 256, 0, stream>>>(s1, deg);
    scan_kernel<<<1, 1024, 0, stream>>>(deg, cursor);
    scatter_kernel<<<(N_EDGES + 255) / 256, 256, 0, stream>>>(
        s0, s1, cursor, perm, ssrc, sdst);

    for (int l = 0; l < NLAYERS; ++l) {
        const size_t wo = (size_t)l * DIM * DIM;
        const size_t bo = (size_t)l * DIM;
        // zero agg + the 6 sum arrays (first 768 floats of stats)
        hipMemsetAsync(agg, 0, ((size_t)N_NODES * DIM + 768) * sizeof(float), stream);

        node_gemm_mfma<<<NG_GRID, 256, 0, stream>>>(
            hbuf, WA + wo, bA + bo, WB + wo, bB + bo, WU + wo, bU + bo,
            WVf + wo, bVf + bo, WVb + wo, bVb + bo,
            Abuf, Bbuf, Ubuf, Vfbuf, Vbbuf);
        edge_gemm_mfma<<<EG_GRID, 256, 0, stream>>>(ebuf, WC + wo, bC + bo, Cbuf);
        edge_stats<<<N_EDGES / ECH, 128, 0, stream>>>(s0, s1, Abuf, Bbuf, Cbuf, stats);
        finalize_edge_stats<<<1, 256, 0, stream>>>(stats);
        edge_apply_sorted<<<N_EDGES / ECH, 128, 0, stream>>>(
            perm, ssrc, sdst, Abuf, Bbuf, Cbuf, Vfbuf, Vbbuf, stats,
            bne_g + bo, bne_b + bo, ebuf, agg);
        node_stats<<<N_NODES / 50, 128, 0, stream>>>(agg, Ubuf, stats);
        finalize_node_stats<<<1, 128, 0, stream>>>(stats);
        node_apply<<<(N_NODES * DIM) / 256, 256, 0, stream>>>(
            agg, Ubuf, stats, bnh_g + bo, bnh_b + bo, hbuf);
    }
}